// Round 9
// baseline (213.346 us; speedup 1.0000x reference)
//
#include <hip/hip_runtime.h>
#include <hip/hip_bf16.h>

#define NROW 8192   // B*A = 64*128
#define INC  128
#define OUTC 64

typedef __bf16 bf16x8 __attribute__((ext_vector_type(8)));
typedef __bf16 bf16x2 __attribute__((ext_vector_type(2)));
typedef float  f32x4  __attribute__((ext_vector_type(4)));

static __device__ __forceinline__ f32x4 mfma16(bf16x8 a, bf16x8 b, f32x4 c) {
    return __builtin_amdgcn_mfma_f32_16x16x32_bf16(a, b, c, 0, 0, 0);
}

static __device__ __forceinline__ bf16x8 cvt8(float4 lo, float4 hi) {
    bf16x8 r;
    r[0] = (__bf16)lo.x; r[1] = (__bf16)lo.y; r[2] = (__bf16)lo.z; r[3] = (__bf16)lo.w;
    r[4] = (__bf16)hi.x; r[5] = (__bf16)hi.y; r[6] = (__bf16)hi.z; r[7] = (__bf16)hi.w;
    return r;
}

static __device__ __forceinline__ int pack_bf2(float a, float b) {
    bf16x2 t; t[0] = (__bf16)a; t[1] = (__bf16)b;
    union { bf16x2 v; int i; } u; u.v = t;
    return u.i;
}

// ---------------------------------------------------------------------------
// Kernel 1: projection via MFMA. grid = 768 = mat(3) x b(64) x aq(4).
__global__ __launch_bounds__(256) void proj_kernel(
    const float* __restrict__ feat,
    const float* __restrict__ Wq, const float* __restrict__ bq,
    const float* __restrict__ Wk, const float* __restrict__ bk,
    const float* __restrict__ Wv, const float* __restrict__ bv,
    __hip_bfloat16* __restrict__ qb, __hip_bfloat16* __restrict__ kb,
    __hip_bfloat16* __restrict__ vT, __hip_bfloat16* __restrict__ vnb)
{
    __shared__ float slab[32 * 132];
    __shared__ float vbuf[32 * 66];
    __shared__ float invb[32];

    const int blk = blockIdx.x;
    const int mat = blk >> 8;
    const int b   = (blk >> 2) & 63;
    const int a0  = (blk & 3) * 32;
    const int r0  = b * 128 + a0;
    const float* fb = feat + (size_t)b * INC * 128;

    for (int i = threadIdx.x; i < 32 * 128; i += 256) {
        int c = i >> 5, a = i & 31;
        slab[a * 132 + c] = fb[c * 128 + a0 + a];
    }
    __syncthreads();

    const int w    = threadIdx.x >> 6;
    const int lane = threadIdx.x & 63;
    const int l16  = lane & 15;
    const int quad = lane >> 4;
    const int n0   = w * 16;

    const float* W    = (mat == 0) ? Wq : (mat == 1) ? Wk : Wv;
    const float* bias = (mat == 0) ? bq : (mat == 1) ? bk : bv;

    f32x4 acc[2] = {{0.f,0.f,0.f,0.f},{0.f,0.f,0.f,0.f}};
    #pragma unroll
    for (int kc = 0; kc < 4; ++kc) {
        const int k0 = kc * 32 + quad * 8;
        const float* wr = W + (n0 + l16) * INC + k0;
        bf16x8 bfr = cvt8(*(const float4*)wr, *(const float4*)(wr + 4));
        #pragma unroll
        for (int u = 0; u < 2; ++u) {
            const float* ar = slab + (u * 16 + l16) * 132 + k0;
            bf16x8 afr = cvt8(*(const float4*)ar, *(const float4*)(ar + 4));
            acc[u] = mfma16(afr, bfr, acc[u]);
        }
    }
    const float bl = bias[n0 + l16];

    if (mat < 2) {
        __hip_bfloat16* dst = mat ? kb : qb;
        #pragma unroll
        for (int u = 0; u < 2; ++u)
            #pragma unroll
            for (int r = 0; r < 4; ++r)
                dst[(r0 + u * 16 + quad * 4 + r) * OUTC + n0 + l16] =
                    __float2bfloat16(acc[u][r] + bl);
    } else {
        #pragma unroll
        for (int u = 0; u < 2; ++u)
            #pragma unroll
            for (int r = 0; r < 4; ++r)
                vbuf[(u * 16 + quad * 4 + r) * 66 + n0 + l16] = acc[u][r] + bl;
        __syncthreads();
        const int c  = threadIdx.x >> 2;
        const int rc = threadIdx.x & 3;
        bf16x8 pack;
        #pragma unroll
        for (int i = 0; i < 8; ++i)
            pack[i] = (__bf16)vbuf[(rc * 8 + i) * 66 + c];
        *(bf16x8*)(vT + (size_t)c * NROW + r0 + rc * 8) = pack;
        const int rl = threadIdx.x >> 3;
        const int jj = threadIdx.x & 7;
        float ss = 0.f;
        #pragma unroll
        for (int i = 0; i < 8; ++i) {
            float x = vbuf[rl * 66 + jj * 8 + i];
            ss += x * x;
        }
        ss += __shfl_xor(ss, 1, 64);
        ss += __shfl_xor(ss, 2, 64);
        ss += __shfl_xor(ss, 4, 64);
        if (jj == 0) invb[rl] = rsqrtf(fmaxf(ss, 1e-24f));
        __syncthreads();
        float inv = invb[rl];
        bf16x8 vp;
        #pragma unroll
        for (int i = 0; i < 8; ++i)
            vp[i] = (__bf16)(vbuf[rl * 66 + jj * 8 + i] * inv);
        *(bf16x8*)(vnb + (size_t)(r0 + rl) * 64 + jj * 8) = vp;
    }
}

// ---------------------------------------------------------------------------
// Kernel 2: attention, cooperative 4-wave blocks, m97-style 2-barrier chunk
// loop. NO cross-barrier register prefetch (r7/r8's pK/pV live-range spanned
// the compute phase -> spills -> 113 MB of scratch HBM writes). Staging regs
// now live only between the two barriers. __launch_bounds__(256,4) caps
// VGPR at 128; 32 KB LDS -> 4 blocks/CU co-resident hide the barrier drain.
__global__ __launch_bounds__(256, 4) void attn_kernel(
    const __hip_bfloat16* __restrict__ qb,
    const __hip_bfloat16* __restrict__ kb,
    const __hip_bfloat16* __restrict__ vT,
    float* __restrict__ Opart, float* __restrict__ lpart)
{
    __shared__ __align__(16) char klds[128 * 128];  // [key][seg^(key&7)]  16 KB
    __shared__ __align__(16) char vlds[64 * 256];   // [t][seg^(t&15)]     16 KB

    const int tid  = threadIdx.x;
    const int w    = tid >> 6;
    const int lane = tid & 63;
    const int l16  = lane & 15;
    const int quad = lane >> 4;
    const int qblk = blockIdx.x & 63;
    const int g    = blockIdx.x >> 6;
    const int r0   = qblk * 128 + w * 32;
    const int key0 = g * 512;

    const int krow = tid >> 3;
    const int kcol = tid & 7;
    const int vrow = tid >> 4;
    const int vcol = tid & 15;
    const int kgsw = (kcol ^ (krow & 7)) * 16;
    const int vgsw = (vcol ^ (vrow & 15)) * 16;

    bf16x8 qf[2][2];
    #pragma unroll
    for (int u = 0; u < 2; ++u)
        #pragma unroll
        for (int kc = 0; kc < 2; ++kc)
            qf[u][kc] = *(const bf16x8*)(qb + (r0 + u * 16 + l16) * 64 + kc * 32 + quad * 8);

    f32x4 of[2][4];
    float lp[2] = {0.f, 0.f};
    #pragma unroll
    for (int u = 0; u < 2; ++u)
        #pragma unroll
        for (int n = 0; n < 4; ++n)
            of[u][n] = (f32x4){0.f, 0.f, 0.f, 0.f};

    const float coef = 0.18033688011112042f;   // log2(e) / sqrt(64)

    const int idx0 = (((quad & 1) << 5) + l16) << 2;
    const int idx1 = idx0 + 64;
    const bool hsel = quad >= 2;

    const char* kbase = (const char*)kb;
    const char* vbase = (const char*)vT;

    for (int cc = 0; cc < 4; ++cc) {
        const int c0 = key0 + cc * 128;
        // staging loads: live range ends at the ds_writes below (no spills)
        float4 sK[4], sV[4];
        #pragma unroll
        for (int i = 0; i < 4; ++i) {
            sK[i] = *(const float4*)(kbase + (size_t)(c0 + i * 32 + krow) * 128 + kgsw);
            sV[i] = *(const float4*)(vbase + (size_t)(i * 16 + vrow) * (NROW * 2)
                                     + (size_t)c0 * 2 + vgsw);
        }
        __syncthreads();   // previous chunk's LDS reads complete
        #pragma unroll
        for (int i = 0; i < 4; ++i) {
            *(float4*)(klds + (i * 32 + krow) * 128 + kcol * 16) = sK[i];
            *(float4*)(vlds + (i * 16 + vrow) * 256 + vcol * 16) = sV[i];
        }
        __syncthreads();   // staging visible

        #pragma unroll
        for (int s = 0; s < 4; ++s) {
            bf16x8 kf[2][2];
            #pragma unroll
            for (int h = 0; h < 2; ++h)
                #pragma unroll
                for (int kc = 0; kc < 2; ++kc)
                    kf[h][kc] = *(const bf16x8*)(klds + (s * 32 + h * 16 + l16) * 128
                                                 + (((kc * 4 + quad) ^ (l16 & 7)) * 16));
            bf16x8 vf[4];
            #pragma unroll
            for (int n = 0; n < 4; ++n)
                vf[n] = *(const bf16x8*)(vlds + (n * 16 + l16) * 256
                                         + (((s * 4 + quad) ^ l16) * 16));

            const f32x4 zero = (f32x4){0.f, 0.f, 0.f, 0.f};
            #pragma unroll
            for (int u = 0; u < 2; ++u) {
                f32x4 s0t = mfma16(kf[0][0], qf[u][0], zero);
                s0t       = mfma16(kf[0][1], qf[u][1], s0t);
                f32x4 s1t = mfma16(kf[1][0], qf[u][0], zero);
                s1t       = mfma16(kf[1][1], qf[u][1], s1t);
                float p[2][4];
                #pragma unroll
                for (int r = 0; r < 4; ++r) {
                    p[0][r] = exp2f(s0t[r] * coef);
                    p[1][r] = exp2f(s1t[r] * coef);
                    lp[u] += p[0][r] + p[1][r];
                }
                int pk0lo = pack_bf2(p[0][0], p[0][1]);
                int pk0hi = pack_bf2(p[0][2], p[0][3]);
                int pk1lo = pack_bf2(p[1][0], p[1][1]);
                int pk1hi = pack_bf2(p[1][2], p[1][3]);
                int a0l = __builtin_amdgcn_ds_bpermute(idx0, pk0lo);
                int a0h = __builtin_amdgcn_ds_bpermute(idx0, pk0hi);
                int a1l = __builtin_amdgcn_ds_bpermute(idx0, pk1lo);
                int a1h = __builtin_amdgcn_ds_bpermute(idx0, pk1hi);
                int b0l = __builtin_amdgcn_ds_bpermute(idx1, pk0lo);
                int b0h = __builtin_amdgcn_ds_bpermute(idx1, pk0hi);
                int b1l = __builtin_amdgcn_ds_bpermute(idx1, pk1lo);
                int b1h = __builtin_amdgcn_ds_bpermute(idx1, pk1hi);
                union { int4 i; bf16x8 v; } cu;
                cu.i.x = hsel ? a1l : a0l;
                cu.i.y = hsel ? a1h : a0h;
                cu.i.z = hsel ? b1l : b0l;
                cu.i.w = hsel ? b1h : b0h;
                bf16x8 pf = cu.v;
                #pragma unroll
                for (int n = 0; n < 4; ++n)
                    of[u][n] = mfma16(pf, vf[n], of[u][n]);
            }
        }
    }

    #pragma unroll
    for (int u = 0; u < 2; ++u) {
        float v = lp[u];
        v += __shfl_xor(v, 16, 64);
        v += __shfl_xor(v, 32, 64);
        lp[u] = v;
    }
    if (quad == 0) {
        lpart[blockIdx.x * 128 + w * 32 + l16]      = lp[0];
        lpart[blockIdx.x * 128 + w * 32 + 16 + l16] = lp[1];
    }
    float* Ob = Opart + (size_t)blockIdx.x * (128 * 64) + (w * 32) * 64;
    #pragma unroll
    for (int u = 0; u < 2; ++u)
        #pragma unroll
        for (int n = 0; n < 4; ++n)
            #pragma unroll
            for (int r = 0; r < 4; ++r)
                Ob[(u * 16 + quad * 4 + r) * 64 + n * 16 + l16] = of[u][n][r];
}

// ---------------------------------------------------------------------------
// Kernel 3: combine split-K partials, divide by l, l2-normalize -> qnb (bf16).
__global__ __launch_bounds__(256) void combine_kernel(
    const float* __restrict__ Opart, const float* __restrict__ lpart,
    __hip_bfloat16* __restrict__ qnb)
{
    const int r    = blockIdx.x * 4 + (threadIdx.x >> 6);
    const int c    = threadIdx.x & 63;
    const int qblk = r >> 7;
    const int lr   = r & 127;
    float acc = 0.f, lsum = 0.f;
    #pragma unroll
    for (int g = 0; g < 16; ++g) {
        int task = g * 64 + qblk;
        acc  += Opart[(size_t)task * 8192 + lr * 64 + c];
        lsum += lpart[task * 128 + lr];
    }
    float q = acc / lsum;
    float ss = q * q;
    ss += __shfl_xor(ss, 1, 64);
    ss += __shfl_xor(ss, 2, 64);
    ss += __shfl_xor(ss, 4, 64);
    ss += __shfl_xor(ss, 8, 64);
    ss += __shfl_xor(ss, 16, 64);
    ss += __shfl_xor(ss, 32, 64);
    qnb[(size_t)r * 64 + c] = __float2bfloat16(q * rsqrtf(fmaxf(ss, 1e-24f)));
}

// ---------------------------------------------------------------------------
// Kernel 4: sim = (1/128) * Vn(64x8192) @ Qn(64x8192)^T, split-K MFMA GEMM.
__global__ __launch_bounds__(64) void sim_kernel(
    const __hip_bfloat16* __restrict__ vnb,
    const __hip_bfloat16* __restrict__ qnb,
    float* __restrict__ out)
{
    const int lane = threadIdx.x;
    const int l16  = lane & 15;
    const int quad = lane >> 4;
    const int kblk = blockIdx.x * 256;

    f32x4 acc[4][4];
    #pragma unroll
    for (int mi = 0; mi < 4; ++mi)
        #pragma unroll
        for (int ni = 0; ni < 4; ++ni)
            acc[mi][ni] = (f32x4){0.f, 0.f, 0.f, 0.f};

    #pragma unroll
    for (int ks = 0; ks < 8; ++ks) {
        const int k0 = kblk + ks * 32 + quad * 8;
        bf16x8 af[4], bfv[4];
        #pragma unroll
        for (int mi = 0; mi < 4; ++mi)
            af[mi] = *(const bf16x8*)(vnb + (size_t)(mi * 16 + l16) * 8192 + k0);
        #pragma unroll
        for (int ni = 0; ni < 4; ++ni)
            bfv[ni] = *(const bf16x8*)(qnb + (size_t)(ni * 16 + l16) * 8192 + k0);
        #pragma unroll
        for (int mi = 0; mi < 4; ++mi)
            #pragma unroll
            for (int ni = 0; ni < 4; ++ni)
                acc[mi][ni] = mfma16(af[mi], bfv[ni], acc[mi][ni]);
    }

    #pragma unroll
    for (int mi = 0; mi < 4; ++mi)
        #pragma unroll
        for (int ni = 0; ni < 4; ++ni)
            #pragma unroll
            for (int r = 0; r < 4; ++r)
                atomicAdd(&out[(mi * 16 + quad * 4 + r) * 64 + ni * 16 + l16],
                          acc[mi][ni][r] * (1.f / 128.f));
}

// ---------------------------------------------------------------------------
extern "C" void kernel_launch(void* const* d_in, const int* in_sizes, int n_in,
                              void* d_out, int out_size, void* d_ws, size_t ws_size,
                              hipStream_t stream)
{
    const float* feat = (const float*)d_in[0];
    const float* Wq   = (const float*)d_in[1];
    const float* bq   = (const float*)d_in[2];
    const float* Wk   = (const float*)d_in[3];
    const float* bk   = (const float*)d_in[4];
    const float* Wv   = (const float*)d_in[5];
    const float* bv   = (const float*)d_in[6];
    float* out = (float*)d_out;

    const size_t MB = 1u << 20;
    char* ws = (char*)d_ws;
    __hip_bfloat16* qb  = (__hip_bfloat16*)(ws);              // 1 MB
    __hip_bfloat16* kb  = (__hip_bfloat16*)(ws + 1 * MB);     // 1 MB
    __hip_bfloat16* vT  = (__hip_bfloat16*)(ws + 2 * MB);     // 1 MB
    __hip_bfloat16* vnb = (__hip_bfloat16*)(ws + 3 * MB);     // 1 MB
    float* Opart = (float*)(ws + 4 * MB);                     // 32 MB (1024 x 32 KB)
    float* lpart = (float*)(ws + 36 * MB);                    // 512 KB
    __hip_bfloat16* qnb = (__hip_bfloat16*)(ws + 37 * MB);    // 1 MB

    (void)hipMemsetAsync(out, 0, 64 * 64 * sizeof(float), stream);
    proj_kernel<<<768, 256, 0, stream>>>(feat, Wq, bq, Wk, bk, Wv, bv, qb, kb, vT, vnb);
    attn_kernel<<<1024, 256, 0, stream>>>(qb, kb, vT, Opart, lpart);
    combine_kernel<<<2048, 256, 0, stream>>>(Opart, lpart, qnb);
    sim_kernel<<<32, 64, 0, stream>>>(vnb, qnb, out);
}

// Round 10
// 135.074 us; speedup vs baseline: 1.5795x; 1.5795x over previous
//
#include <hip/hip_runtime.h>
#include <hip/hip_bf16.h>

#define NROW 8192   // B*A = 64*128
#define INC  128
#define OUTC 64

typedef __bf16 bf16x8 __attribute__((ext_vector_type(8)));
typedef __bf16 bf16x4 __attribute__((ext_vector_type(4)));
typedef short  s16x4  __attribute__((ext_vector_type(4)));
typedef float  f32x4  __attribute__((ext_vector_type(4)));

static __device__ __forceinline__ f32x4 mfma16(bf16x8 a, bf16x8 b, f32x4 c) {
    return __builtin_amdgcn_mfma_f32_16x16x32_bf16(a, b, c, 0, 0, 0);
}
// 16x16x16 bf16 (K=16). C/D of S^T in this shape IS the A-operand layout of P
// for the PV mfma -> no transpose needed between QK^T and PV.
static __device__ __forceinline__ f32x4 mfma1k(s16x4 a, s16x4 b, f32x4 c) {
    return __builtin_amdgcn_mfma_f32_16x16x16bf16_1k(a, b, c, 0, 0, 0);
}

static __device__ __forceinline__ bf16x8 cvt8(float4 lo, float4 hi) {
    bf16x8 r;
    r[0] = (__bf16)lo.x; r[1] = (__bf16)lo.y; r[2] = (__bf16)lo.z; r[3] = (__bf16)lo.w;
    r[4] = (__bf16)hi.x; r[5] = (__bf16)hi.y; r[6] = (__bf16)hi.z; r[7] = (__bf16)hi.w;
    return r;
}

// ---------------------------------------------------------------------------
// Kernel 1: projection via MFMA. grid = 768 = mat(3) x b(64) x aq(4).
// Q/K are written in FRAGMENT-TILED layout for attn: for 16-row chunk c and
// d-chunk kc, a 512-B tile at ((c*4+kc)*256) holding elem[row%16 *16 + d%16].
// V likewise (vbf: tile ((key/16)*4 + t/16)*256, elem[t%16 *16 + key%16]),
// plus row-l2-normalized vnb (row-major) for the sim GEMM.
__global__ __launch_bounds__(256) void proj_kernel(
    const float* __restrict__ feat,
    const float* __restrict__ Wq, const float* __restrict__ bq,
    const float* __restrict__ Wk, const float* __restrict__ bk,
    const float* __restrict__ Wv, const float* __restrict__ bv,
    __hip_bfloat16* __restrict__ qbf, __hip_bfloat16* __restrict__ kbf,
    __hip_bfloat16* __restrict__ vbf, __hip_bfloat16* __restrict__ vnb)
{
    __shared__ float slab[32 * 132];
    __shared__ float vbuf[32 * 66];
    __shared__ float invb[32];

    const int blk = blockIdx.x;
    const int mat = blk >> 8;
    const int b   = (blk >> 2) & 63;
    const int a0  = (blk & 3) * 32;
    const int r0  = b * 128 + a0;
    const float* fb = feat + (size_t)b * INC * 128;

    for (int i = threadIdx.x; i < 32 * 128; i += 256) {
        int c = i >> 5, a = i & 31;
        slab[a * 132 + c] = fb[c * 128 + a0 + a];
    }
    __syncthreads();

    const int w    = threadIdx.x >> 6;
    const int lane = threadIdx.x & 63;
    const int l16  = lane & 15;
    const int quad = lane >> 4;
    const int n0   = w * 16;

    const float* W    = (mat == 0) ? Wq : (mat == 1) ? Wk : Wv;
    const float* bias = (mat == 0) ? bq : (mat == 1) ? bk : bv;

    f32x4 acc[2] = {{0.f,0.f,0.f,0.f},{0.f,0.f,0.f,0.f}};
    #pragma unroll
    for (int kc = 0; kc < 4; ++kc) {
        const int k0 = kc * 32 + quad * 8;
        const float* wr = W + (n0 + l16) * INC + k0;
        bf16x8 bfr = cvt8(*(const float4*)wr, *(const float4*)(wr + 4));
        #pragma unroll
        for (int u = 0; u < 2; ++u) {
            const float* ar = slab + (u * 16 + l16) * 132 + k0;
            bf16x8 afr = cvt8(*(const float4*)ar, *(const float4*)(ar + 4));
            acc[u] = mfma16(afr, bfr, acc[u]);
        }
    }
    const float bl = bias[n0 + l16];

    if (mat < 2) {
        // frag-tiled store: row = r0+u*16+quad*4+r (chunk=(r0>>4)+u), d = n0+l16
        __hip_bfloat16* dst = mat ? kbf : qbf;
        #pragma unroll
        for (int u = 0; u < 2; ++u) {
            const int base = ((((r0 >> 4) + u) * 4 + w) << 8) + l16;
            #pragma unroll
            for (int r = 0; r < 4; ++r)
                dst[base + (quad * 4 + r) * 16] = __float2bfloat16(acc[u][r] + bl);
        }
    } else {
        #pragma unroll
        for (int u = 0; u < 2; ++u)
            #pragma unroll
            for (int r = 0; r < 4; ++r)
                vbuf[(u * 16 + quad * 4 + r) * 66 + n0 + l16] = acc[u][r] + bl;
        __syncthreads();
        // row norms
        const int rl = threadIdx.x >> 3;
        const int jj = threadIdx.x & 7;
        float ss = 0.f;
        #pragma unroll
        for (int i = 0; i < 8; ++i) {
            float x = vbuf[rl * 66 + jj * 8 + i];
            ss += x * x;
        }
        ss += __shfl_xor(ss, 1, 64);
        ss += __shfl_xor(ss, 2, 64);
        ss += __shfl_xor(ss, 4, 64);
        if (jj == 0) invb[rl] = rsqrtf(fmaxf(ss, 1e-24f));
        __syncthreads();
        // vnb (row-major normalized, for sim)
        float inv = invb[rl];
        bf16x8 vp;
        #pragma unroll
        for (int i = 0; i < 8; ++i)
            vp[i] = (__bf16)(vbuf[rl * 66 + jj * 8 + i] * inv);
        *(bf16x8*)(vnb + (size_t)(r0 + rl) * 64 + jj * 8) = vp;
        // vbf frag-tiled store: thread -> (tl=t%16, n=t/16, s_= key-octet)
        const int tl = threadIdx.x & 15;
        const int n  = (threadIdx.x >> 4) & 3;
        const int s_ = threadIdx.x >> 6;
        bf16x8 pack;
        #pragma unroll
        for (int j = 0; j < 8; ++j) {
            int key = s_ * 8 + j;
            pack[j] = (__bf16)(vbuf[key * 66 + n * 16 + tl] * invb[key]);
        }
        const int base = ((((r0 >> 4) + (s_ >> 1)) * 4 + n) << 8) + tl * 16 + (s_ & 1) * 8;
        *(bf16x8*)(vbf + base) = pack;
    }
}

// ---------------------------------------------------------------------------
// Kernel 2: attention — single-wave blocks (no-spill r5 shape), K=16 MFMAs,
// NO P transpose: S^T's C-layout == P's A-layout for PV. No LDS, no barriers.
// grid = 4096 = G(16) x tile(256); wave owns 32 q-rows x 512 keys.
// K frags register-double-buffered one iter ahead; V frags issued at iter top
// (consumed after S+exp2, ~300 cyc later). All frag loads are contiguous
// 512-B wave loads thanks to proj's frag-tiled layouts.
__global__ __launch_bounds__(64) void attn_kernel(
    const __hip_bfloat16* __restrict__ qbf,
    const __hip_bfloat16* __restrict__ kbf,
    const __hip_bfloat16* __restrict__ vbf,
    float* __restrict__ Opart, float* __restrict__ lpart)
{
    const int task = blockIdx.x;
    const int tile = task & 255;
    const int g    = task >> 8;
    const int r0   = tile * 32;
    const int lane = threadIdx.x;
    const int l16  = lane & 15;
    const int quad = lane >> 4;
    const int fo   = l16 * 16 + quad * 4;   // elem offset inside a 256-elem tile

    s16x4 qf[2][4];
    #pragma unroll
    for (int u = 0; u < 2; ++u)
        #pragma unroll
        for (int kc = 0; kc < 4; ++kc)
            qf[u][kc] = *(const s16x4*)(qbf + ((((r0 >> 4) + u) * 4 + kc) << 8) + fo);

    f32x4 of[2][4];
    float lp[2] = {0.f, 0.f};
    #pragma unroll
    for (int u = 0; u < 2; ++u)
        #pragma unroll
        for (int n = 0; n < 4; ++n)
            of[u][n] = (f32x4){0.f, 0.f, 0.f, 0.f};

    const float coef = 0.18033688011112042f;   // log2(e) / sqrt(64)

    int ck = (g * 512) >> 4;                   // key 16-chunk index
    s16x4 kf[2][4];
    #pragma unroll
    for (int h = 0; h < 2; ++h)
        #pragma unroll
        for (int kc = 0; kc < 4; ++kc)
            kf[h][kc] = *(const s16x4*)(kbf + (((ck + h) * 4 + kc) << 8) + fo);

    #pragma unroll 1
    for (int it = 0; it < 16; ++it) {
        // V frags for current 32 keys (consumed after S+exp2)
        s16x4 vf[4][2];
        #pragma unroll
        for (int n = 0; n < 4; ++n)
            #pragma unroll
            for (int h = 0; h < 2; ++h)
                vf[n][h] = *(const s16x4*)(vbf + (((ck + h) * 4 + n) << 8) + fo);
        // prefetch next iter's K
        const int cn = (it < 15) ? ck + 2 : ck;
        s16x4 kn[2][4];
        #pragma unroll
        for (int h = 0; h < 2; ++h)
            #pragma unroll
            for (int kc = 0; kc < 4; ++kc)
                kn[h][kc] = *(const s16x4*)(kbf + (((cn + h) * 4 + kc) << 8) + fo);

        const f32x4 zero = (f32x4){0.f, 0.f, 0.f, 0.f};
        #pragma unroll
        for (int u = 0; u < 2; ++u) {
            // S^T tiles (key-major): D[key=quad*4+r][qrow=l16]
            f32x4 s0 = zero, s1 = zero;
            #pragma unroll
            for (int kc = 0; kc < 4; ++kc) {
                s0 = mfma1k(kf[0][kc], qf[u][kc], s0);
                s1 = mfma1k(kf[1][kc], qf[u][kc], s1);
            }
            union { bf16x4 v; s16x4 s; } pf0, pf1;
            #pragma unroll
            for (int r = 0; r < 4; ++r) {
                float p0 = exp2f(s0[r] * coef);
                float p1 = exp2f(s1[r] * coef);
                lp[u] += p0 + p1;
                pf0.v[r] = (__bf16)p0;
                pf1.v[r] = (__bf16)p1;
            }
            // PV: P already in A-layout (A[m=qrow=l16][k=key=quad*4+i])
            #pragma unroll
            for (int n = 0; n < 4; ++n) {
                of[u][n] = mfma1k(pf0.s, vf[n][0], of[u][n]);
                of[u][n] = mfma1k(pf1.s, vf[n][1], of[u][n]);
            }
        }
        #pragma unroll
        for (int h = 0; h < 2; ++h)
            #pragma unroll
            for (int kc = 0; kc < 4; ++kc)
                kf[h][kc] = kn[h][kc];
        ck += 2;
    }

    // l: per-lane partial covers keys {quad*4+r, h}; reduce across quads
    #pragma unroll
    for (int u = 0; u < 2; ++u) {
        float v = lp[u];
        v += __shfl_xor(v, 16, 64);
        v += __shfl_xor(v, 32, 64);
        lp[u] = v;
    }
    if (quad == 0) {
        lpart[task * 32 + l16]      = lp[0];
        lpart[task * 32 + 16 + l16] = lp[1];
    }
    // of C-layout: O[r0+u*16+quad*4+r][n*16+l16]
    float* Ob = Opart + (size_t)task * 32 * 64;
    #pragma unroll
    for (int u = 0; u < 2; ++u)
        #pragma unroll
        for (int n = 0; n < 4; ++n)
            #pragma unroll
            for (int r = 0; r < 4; ++r)
                Ob[(u * 16 + quad * 4 + r) * 64 + n * 16 + l16] = of[u][n][r];
}

// ---------------------------------------------------------------------------
// Kernel 3: combine split-K partials, divide by l, l2-normalize -> qnb (bf16).
__global__ __launch_bounds__(256) void combine_kernel(
    const float* __restrict__ Opart, const float* __restrict__ lpart,
    __hip_bfloat16* __restrict__ qnb)
{
    const int r    = blockIdx.x * 4 + (threadIdx.x >> 6);
    const int c    = threadIdx.x & 63;
    const int tile = r >> 5, row = r & 31;
    float acc = 0.f, lsum = 0.f;
    #pragma unroll
    for (int g = 0; g < 16; ++g) {
        int task = g * 256 + tile;
        acc  += Opart[((size_t)task * 32 + row) * 64 + c];
        lsum += lpart[task * 32 + row];
    }
    float q = acc / lsum;
    float ss = q * q;
    ss += __shfl_xor(ss, 1, 64);
    ss += __shfl_xor(ss, 2, 64);
    ss += __shfl_xor(ss, 4, 64);
    ss += __shfl_xor(ss, 8, 64);
    ss += __shfl_xor(ss, 16, 64);
    ss += __shfl_xor(ss, 32, 64);
    qnb[(size_t)r * 64 + c] = __float2bfloat16(q * rsqrtf(fmaxf(ss, 1e-24f)));
}

// ---------------------------------------------------------------------------
// Kernel 4: sim = (1/128) * Vn(64x8192) @ Qn(64x8192)^T, split-K MFMA GEMM.
__global__ __launch_bounds__(64) void sim_kernel(
    const __hip_bfloat16* __restrict__ vnb,
    const __hip_bfloat16* __restrict__ qnb,
    float* __restrict__ out)
{
    const int lane = threadIdx.x;
    const int l16  = lane & 15;
    const int quad = lane >> 4;
    const int kblk = blockIdx.x * 256;

    f32x4 acc[4][4];
    #pragma unroll
    for (int mi = 0; mi < 4; ++mi)
        #pragma unroll
        for (int ni = 0; ni < 4; ++ni)
            acc[mi][ni] = (f32x4){0.f, 0.f, 0.f, 0.f};

    #pragma unroll
    for (int ks = 0; ks < 8; ++ks) {
        const int k0 = kblk + ks * 32 + quad * 8;
        bf16x8 af[4], bfv[4];
        #pragma unroll
        for (int mi = 0; mi < 4; ++mi)
            af[mi] = *(const bf16x8*)(vnb + (size_t)(mi * 16 + l16) * 8192 + k0);
        #pragma unroll
        for (int ni = 0; ni < 4; ++ni)
            bfv[ni] = *(const bf16x8*)(qnb + (size_t)(ni * 16 + l16) * 8192 + k0);
        #pragma unroll
        for (int mi = 0; mi < 4; ++mi)
            #pragma unroll
            for (int ni = 0; ni < 4; ++ni)
                acc[mi][ni] = mfma16(af[mi], bfv[ni], acc[mi][ni]);
    }

    #pragma unroll
    for (int mi = 0; mi < 4; ++mi)
        #pragma unroll
        for (int ni = 0; ni < 4; ++ni)
            #pragma unroll
            for (int r = 0; r < 4; ++r)
                atomicAdd(&out[(mi * 16 + quad * 4 + r) * 64 + ni * 16 + l16],
                          acc[mi][ni][r] * (1.f / 128.f));
}

// ---------------------------------------------------------------------------
extern "C" void kernel_launch(void* const* d_in, const int* in_sizes, int n_in,
                              void* d_out, int out_size, void* d_ws, size_t ws_size,
                              hipStream_t stream)
{
    const float* feat = (const float*)d_in[0];
    const float* Wq   = (const float*)d_in[1];
    const float* bq   = (const float*)d_in[2];
    const float* Wk   = (const float*)d_in[3];
    const float* bk   = (const float*)d_in[4];
    const float* Wv   = (const float*)d_in[5];
    const float* bv   = (const float*)d_in[6];
    float* out = (float*)d_out;

    const size_t MB = 1u << 20;
    char* ws = (char*)d_ws;
    __hip_bfloat16* qbf = (__hip_bfloat16*)(ws);              // 1 MB (frag-tiled)
    __hip_bfloat16* kbf = (__hip_bfloat16*)(ws + 1 * MB);     // 1 MB (frag-tiled)
    __hip_bfloat16* vbf = (__hip_bfloat16*)(ws + 2 * MB);     // 1 MB (frag-tiled)
    __hip_bfloat16* vnb = (__hip_bfloat16*)(ws + 3 * MB);     // 1 MB (row-major)
    float* Opart = (float*)(ws + 4 * MB);                     // 32 MB (4096 x 8 KB)
    float* lpart = (float*)(ws + 36 * MB);                    // 512 KB
    __hip_bfloat16* qnb = (__hip_bfloat16*)(ws + 37 * MB);    // 1 MB

    (void)hipMemsetAsync(out, 0, 64 * 64 * sizeof(float), stream);
    proj_kernel<<<768, 256, 0, stream>>>(feat, Wq, bq, Wk, bk, Wv, bv, qbf, kbf, vbf, vnb);
    attn_kernel<<<4096, 64, 0, stream>>>(qbf, kbf, vbf, Opart, lpart);
    combine_kernel<<<2048, 256, 0, stream>>>(Opart, lpart, qnb);
    sim_kernel<<<32, 64, 0, stream>>>(vnb, qnb, out);
}

// Round 11
// 124.854 us; speedup vs baseline: 1.7088x; 1.0819x over previous
//
#include <hip/hip_runtime.h>
#include <hip/hip_bf16.h>

#define NROW 8192   // B*A = 64*128
#define INC  128
#define OUTC 64

typedef __bf16 bf16x8 __attribute__((ext_vector_type(8)));
typedef __bf16 bf16x4 __attribute__((ext_vector_type(4)));
typedef short  s16x4  __attribute__((ext_vector_type(4)));
typedef float  f32x4  __attribute__((ext_vector_type(4)));

static __device__ __forceinline__ f32x4 mfma16(bf16x8 a, bf16x8 b, f32x4 c) {
    return __builtin_amdgcn_mfma_f32_16x16x32_bf16(a, b, c, 0, 0, 0);
}
// 16x16x16 bf16 (K=16). C/D of S^T in this shape IS the A-operand layout of P
// for the PV mfma -> no transpose needed between QK^T and PV.
static __device__ __forceinline__ f32x4 mfma1k(s16x4 a, s16x4 b, f32x4 c) {
    return __builtin_amdgcn_mfma_f32_16x16x16bf16_1k(a, b, c, 0, 0, 0);
}

static __device__ __forceinline__ bf16x8 cvt8(float4 lo, float4 hi) {
    bf16x8 r;
    r[0] = (__bf16)lo.x; r[1] = (__bf16)lo.y; r[2] = (__bf16)lo.z; r[3] = (__bf16)lo.w;
    r[4] = (__bf16)hi.x; r[5] = (__bf16)hi.y; r[6] = (__bf16)hi.z; r[7] = (__bf16)hi.w;
    return r;
}

// ---------------------------------------------------------------------------
// Kernel 1: projection via MFMA. grid = 768 = mat(3) x b(64) x aq(4).
// Q/K/V written in FRAGMENT-TILED layout for attn (512-B tiles, see r10),
// plus row-l2-normalized vnb (row-major) for the sim GEMM.
__global__ __launch_bounds__(256) void proj_kernel(
    const float* __restrict__ feat,
    const float* __restrict__ Wq, const float* __restrict__ bq,
    const float* __restrict__ Wk, const float* __restrict__ bk,
    const float* __restrict__ Wv, const float* __restrict__ bv,
    __hip_bfloat16* __restrict__ qbf, __hip_bfloat16* __restrict__ kbf,
    __hip_bfloat16* __restrict__ vbf, __hip_bfloat16* __restrict__ vnb)
{
    __shared__ float slab[32 * 132];
    __shared__ float vbuf[32 * 66];
    __shared__ float invb[32];

    const int blk = blockIdx.x;
    const int mat = blk >> 8;
    const int b   = (blk >> 2) & 63;
    const int a0  = (blk & 3) * 32;
    const int r0  = b * 128 + a0;
    const float* fb = feat + (size_t)b * INC * 128;

    for (int i = threadIdx.x; i < 32 * 128; i += 256) {
        int c = i >> 5, a = i & 31;
        slab[a * 132 + c] = fb[c * 128 + a0 + a];
    }
    __syncthreads();

    const int w    = threadIdx.x >> 6;
    const int lane = threadIdx.x & 63;
    const int l16  = lane & 15;
    const int quad = lane >> 4;
    const int n0   = w * 16;

    const float* W    = (mat == 0) ? Wq : (mat == 1) ? Wk : Wv;
    const float* bias = (mat == 0) ? bq : (mat == 1) ? bk : bv;

    f32x4 acc[2] = {{0.f,0.f,0.f,0.f},{0.f,0.f,0.f,0.f}};
    #pragma unroll
    for (int kc = 0; kc < 4; ++kc) {
        const int k0 = kc * 32 + quad * 8;
        const float* wr = W + (n0 + l16) * INC + k0;
        bf16x8 bfr = cvt8(*(const float4*)wr, *(const float4*)(wr + 4));
        #pragma unroll
        for (int u = 0; u < 2; ++u) {
            const float* ar = slab + (u * 16 + l16) * 132 + k0;
            bf16x8 afr = cvt8(*(const float4*)ar, *(const float4*)(ar + 4));
            acc[u] = mfma16(afr, bfr, acc[u]);
        }
    }
    const float bl = bias[n0 + l16];

    if (mat < 2) {
        __hip_bfloat16* dst = mat ? kbf : qbf;
        #pragma unroll
        for (int u = 0; u < 2; ++u) {
            const int base = ((((r0 >> 4) + u) * 4 + w) << 8) + l16;
            #pragma unroll
            for (int r = 0; r < 4; ++r)
                dst[base + (quad * 4 + r) * 16] = __float2bfloat16(acc[u][r] + bl);
        }
    } else {
        #pragma unroll
        for (int u = 0; u < 2; ++u)
            #pragma unroll
            for (int r = 0; r < 4; ++r)
                vbuf[(u * 16 + quad * 4 + r) * 66 + n0 + l16] = acc[u][r] + bl;
        __syncthreads();
        const int rl = threadIdx.x >> 3;
        const int jj = threadIdx.x & 7;
        float ss = 0.f;
        #pragma unroll
        for (int i = 0; i < 8; ++i) {
            float x = vbuf[rl * 66 + jj * 8 + i];
            ss += x * x;
        }
        ss += __shfl_xor(ss, 1, 64);
        ss += __shfl_xor(ss, 2, 64);
        ss += __shfl_xor(ss, 4, 64);
        if (jj == 0) invb[rl] = rsqrtf(fmaxf(ss, 1e-24f));
        __syncthreads();
        float inv = invb[rl];
        bf16x8 vp;
        #pragma unroll
        for (int i = 0; i < 8; ++i)
            vp[i] = (__bf16)(vbuf[rl * 66 + jj * 8 + i] * inv);
        *(bf16x8*)(vnb + (size_t)(r0 + rl) * 64 + jj * 8) = vp;
        const int tl = threadIdx.x & 15;
        const int n  = (threadIdx.x >> 4) & 3;
        const int s_ = threadIdx.x >> 6;
        bf16x8 pack;
        #pragma unroll
        for (int j = 0; j < 8; ++j) {
            int key = s_ * 8 + j;
            pack[j] = (__bf16)(vbuf[key * 66 + n * 16 + tl] * invb[key]);
        }
        const int base = ((((r0 >> 4) + (s_ >> 1)) * 4 + n) << 8) + tl * 16 + (s_ & 1) * 8;
        *(bf16x8*)(vbf + base) = pack;
    }
}

// ---------------------------------------------------------------------------
// Kernel 2: attention — r10's K=16 no-transpose register pipeline, now in
// 4-wave blocks with in-block LDS reduction of partials (epilogue-only LDS).
// grid = 512 = qtile(256) x bg(2). Wave w owns keys [bg*4096 + w*1024, +1024)
// = 32 iters of 32 keys. Block writes ONE 32x64 fp32 partial (Opart 4 MB
// instead of 32 MB; combine g-loop 16 -> 2).
__global__ __launch_bounds__(256) void attn_kernel(
    const __hip_bfloat16* __restrict__ qbf,
    const __hip_bfloat16* __restrict__ kbf,
    const __hip_bfloat16* __restrict__ vbf,
    float* __restrict__ Opart, float* __restrict__ lpart)
{
    __shared__ float ored[4][32][65];   // [wave][row][col], pad-65
    __shared__ float lred[4][32];

    const int qtile = blockIdx.x >> 1;
    const int bg    = blockIdx.x & 1;
    const int w     = threadIdx.x >> 6;
    const int lane  = threadIdx.x & 63;
    const int l16   = lane & 15;
    const int quad  = lane >> 4;
    const int r0    = qtile * 32;
    const int fo    = l16 * 16 + quad * 4;   // elem offset inside a 256-elem tile

    s16x4 qf[2][4];
    #pragma unroll
    for (int u = 0; u < 2; ++u)
        #pragma unroll
        for (int kc = 0; kc < 4; ++kc)
            qf[u][kc] = *(const s16x4*)(qbf + ((((r0 >> 4) + u) * 4 + kc) << 8) + fo);

    f32x4 of[2][4];
    float lp[2] = {0.f, 0.f};
    #pragma unroll
    for (int u = 0; u < 2; ++u)
        #pragma unroll
        for (int n = 0; n < 4; ++n)
            of[u][n] = (f32x4){0.f, 0.f, 0.f, 0.f};

    const float coef = 0.18033688011112042f;   // log2(e) / sqrt(64)

    int ck = bg * 256 + w * 64;                // key 16-chunk index
    s16x4 kf[2][4];
    #pragma unroll
    for (int h = 0; h < 2; ++h)
        #pragma unroll
        for (int kc = 0; kc < 4; ++kc)
            kf[h][kc] = *(const s16x4*)(kbf + (((ck + h) * 4 + kc) << 8) + fo);

    #pragma unroll 1
    for (int it = 0; it < 32; ++it) {
        s16x4 vf[4][2];
        #pragma unroll
        for (int n = 0; n < 4; ++n)
            #pragma unroll
            for (int h = 0; h < 2; ++h)
                vf[n][h] = *(const s16x4*)(vbf + (((ck + h) * 4 + n) << 8) + fo);
        const int cn = (it < 31) ? ck + 2 : ck;
        s16x4 kn[2][4];
        #pragma unroll
        for (int h = 0; h < 2; ++h)
            #pragma unroll
            for (int kc = 0; kc < 4; ++kc)
                kn[h][kc] = *(const s16x4*)(kbf + (((cn + h) * 4 + kc) << 8) + fo);

        const f32x4 zero = (f32x4){0.f, 0.f, 0.f, 0.f};
        #pragma unroll
        for (int u = 0; u < 2; ++u) {
            f32x4 s0 = zero, s1 = zero;
            #pragma unroll
            for (int kc = 0; kc < 4; ++kc) {
                s0 = mfma1k(kf[0][kc], qf[u][kc], s0);
                s1 = mfma1k(kf[1][kc], qf[u][kc], s1);
            }
            union { bf16x4 v; s16x4 s; } pf0, pf1;
            #pragma unroll
            for (int r = 0; r < 4; ++r) {
                float p0 = exp2f(s0[r] * coef);
                float p1 = exp2f(s1[r] * coef);
                lp[u] += p0 + p1;
                pf0.v[r] = (__bf16)p0;
                pf1.v[r] = (__bf16)p1;
            }
            #pragma unroll
            for (int n = 0; n < 4; ++n) {
                of[u][n] = mfma1k(pf0.s, vf[n][0], of[u][n]);
                of[u][n] = mfma1k(pf1.s, vf[n][1], of[u][n]);
            }
        }
        #pragma unroll
        for (int h = 0; h < 2; ++h)
            #pragma unroll
            for (int kc = 0; kc < 4; ++kc)
                kf[h][kc] = kn[h][kc];
        ck += 2;
    }

    // per-wave l reduction across quads, stash in LDS
    #pragma unroll
    for (int u = 0; u < 2; ++u) {
        float v = lp[u];
        v += __shfl_xor(v, 16, 64);
        v += __shfl_xor(v, 32, 64);
        lp[u] = v;
    }
    if (quad == 0) {
        lred[w][l16]      = lp[0];
        lred[w][16 + l16] = lp[1];
    }
    // O partial to LDS (C-layout rows; pad-65 -> conflict-free)
    #pragma unroll
    for (int u = 0; u < 2; ++u)
        #pragma unroll
        for (int n = 0; n < 4; ++n)
            #pragma unroll
            for (int r = 0; r < 4; ++r)
                ored[w][u * 16 + quad * 4 + r][n * 16 + l16] = of[u][n][r];
    __syncthreads();

    // 4-way reduce, stream one 32x64 partial per block
    const int task = blockIdx.x;      // qtile*2 + bg
    float* Ob = Opart + (size_t)task * 2048;
    for (int e = threadIdx.x; e < 2048; e += 256) {
        const int row = e >> 6, col = e & 63;
        Ob[e] = ored[0][row][col] + ored[1][row][col]
              + ored[2][row][col] + ored[3][row][col];
    }
    if (threadIdx.x < 32)
        lpart[task * 32 + threadIdx.x] =
            lred[0][threadIdx.x] + lred[1][threadIdx.x]
          + lred[2][threadIdx.x] + lred[3][threadIdx.x];
}

// ---------------------------------------------------------------------------
// Kernel 3: combine 2 partials/tile, divide by l, l2-normalize -> qnb (bf16).
__global__ __launch_bounds__(256) void combine_kernel(
    const float* __restrict__ Opart, const float* __restrict__ lpart,
    __hip_bfloat16* __restrict__ qnb)
{
    const int r    = blockIdx.x * 4 + (threadIdx.x >> 6);
    const int c    = threadIdx.x & 63;
    const int tile = r >> 5, row = r & 31;
    float acc = 0.f, lsum = 0.f;
    #pragma unroll
    for (int g = 0; g < 2; ++g) {
        int task = tile * 2 + g;
        acc  += Opart[(size_t)task * 2048 + row * 64 + c];
        lsum += lpart[task * 32 + row];
    }
    float q = acc / lsum;
    float ss = q * q;
    ss += __shfl_xor(ss, 1, 64);
    ss += __shfl_xor(ss, 2, 64);
    ss += __shfl_xor(ss, 4, 64);
    ss += __shfl_xor(ss, 8, 64);
    ss += __shfl_xor(ss, 16, 64);
    ss += __shfl_xor(ss, 32, 64);
    qnb[(size_t)r * 64 + c] = __float2bfloat16(q * rsqrtf(fmaxf(ss, 1e-24f)));
}

// ---------------------------------------------------------------------------
// Kernel 4: sim = (1/128) * Vn(64x8192) @ Qn(64x8192)^T, split-K MFMA GEMM.
__global__ __launch_bounds__(64) void sim_kernel(
    const __hip_bfloat16* __restrict__ vnb,
    const __hip_bfloat16* __restrict__ qnb,
    float* __restrict__ out)
{
    const int lane = threadIdx.x;
    const int l16  = lane & 15;
    const int quad = lane >> 4;
    const int kblk = blockIdx.x * 256;

    f32x4 acc[4][4];
    #pragma unroll
    for (int mi = 0; mi < 4; ++mi)
        #pragma unroll
        for (int ni = 0; ni < 4; ++ni)
            acc[mi][ni] = (f32x4){0.f, 0.f, 0.f, 0.f};

    #pragma unroll
    for (int ks = 0; ks < 8; ++ks) {
        const int k0 = kblk + ks * 32 + quad * 8;
        bf16x8 af[4], bfv[4];
        #pragma unroll
        for (int mi = 0; mi < 4; ++mi)
            af[mi] = *(const bf16x8*)(vnb + (size_t)(mi * 16 + l16) * 8192 + k0);
        #pragma unroll
        for (int ni = 0; ni < 4; ++ni)
            bfv[ni] = *(const bf16x8*)(qnb + (size_t)(ni * 16 + l16) * 8192 + k0);
        #pragma unroll
        for (int mi = 0; mi < 4; ++mi)
            #pragma unroll
            for (int ni = 0; ni < 4; ++ni)
                acc[mi][ni] = mfma16(af[mi], bfv[ni], acc[mi][ni]);
    }

    #pragma unroll
    for (int mi = 0; mi < 4; ++mi)
        #pragma unroll
        for (int ni = 0; ni < 4; ++ni)
            #pragma unroll
            for (int r = 0; r < 4; ++r)
                atomicAdd(&out[(mi * 16 + quad * 4 + r) * 64 + ni * 16 + l16],
                          acc[mi][ni][r] * (1.f / 128.f));
}

// ---------------------------------------------------------------------------
extern "C" void kernel_launch(void* const* d_in, const int* in_sizes, int n_in,
                              void* d_out, int out_size, void* d_ws, size_t ws_size,
                              hipStream_t stream)
{
    const float* feat = (const float*)d_in[0];
    const float* Wq   = (const float*)d_in[1];
    const float* bq   = (const float*)d_in[2];
    const float* Wk   = (const float*)d_in[3];
    const float* bk   = (const float*)d_in[4];
    const float* Wv   = (const float*)d_in[5];
    const float* bv   = (const float*)d_in[6];
    float* out = (float*)d_out;

    const size_t MB = 1u << 20;
    char* ws = (char*)d_ws;
    __hip_bfloat16* qbf = (__hip_bfloat16*)(ws);              // 1 MB (frag-tiled)
    __hip_bfloat16* kbf = (__hip_bfloat16*)(ws + 1 * MB);     // 1 MB (frag-tiled)
    __hip_bfloat16* vbf = (__hip_bfloat16*)(ws + 2 * MB);     // 1 MB (frag-tiled)
    __hip_bfloat16* vnb = (__hip_bfloat16*)(ws + 3 * MB);     // 1 MB (row-major)
    float* Opart = (float*)(ws + 4 * MB);                     // 4 MB (512 x 8 KB)
    float* lpart = (float*)(ws + 8 * MB);                     // 64 KB
    __hip_bfloat16* qnb = (__hip_bfloat16*)(ws + 9 * MB);     // 1 MB

    (void)hipMemsetAsync(out, 0, 64 * 64 * sizeof(float), stream);
    proj_kernel<<<768, 256, 0, stream>>>(feat, Wq, bq, Wk, bk, Wv, bv, qbf, kbf, vbf, vnb);
    attn_kernel<<<512, 256, 0, stream>>>(qbf, kbf, vbf, Opart, lpart);
    combine_kernel<<<2048, 256, 0, stream>>>(Opart, lpart, qnb);
    sim_kernel<<<32, 64, 0, stream>>>(vnb, qnb, out);
}